// Round 8
// baseline (1509.321 us; speedup 1.0000x reference)
//
#include <hip/hip_runtime.h>

// GRU scan: T=1024, B=256, D=256.
// v8: v7 fused producer/consumer + two scan fixes:
//  (1) pair-sequential MFMA (Z->R->N) with gate VALU of pair i placed after
//      pair i+1's MFMAs -> sigmoid/fold hides under the MFMA pipe; only the
//      n-gate tail is exposed.
//  (2) hb16 row pitch 512->576 B: batch row b=1 lands on banks 16-31 ->
//      frag reads and merged h-writes fully bank-conflict-free (was 35.6M).

typedef __attribute__((ext_vector_type(8))) short short8;
typedef __attribute__((ext_vector_type(4))) float f32x4;

#define T_DIM 1024
#define B_DIM 256
#define D_DIM 256
#define SCL_RZ (-1.44269504f)   // -log2(e): sigm(x) = 1/(1+exp2(x*SCL_RZ))
#define SCL_N  (2.88539008f)    // 2*log2(e): tanh(v) = 1-2/(1+exp2(v*SCL_N))
#define HP 576                  // hb16 row pitch (bytes): +64B bank skew
#define HBUF 1152               // one h double-buffer half (2 rows x 576)

__device__ __forceinline__ unsigned short f2bf(float f) {
  union { float f; unsigned u; } c; c.f = f;
  unsigned r = c.u + 0x7FFFu + ((c.u >> 16) & 1u);  // RNE
  return (unsigned short)(r >> 16);
}
__device__ __forceinline__ float u2f(unsigned u) {
  union { unsigned u; float f; } c; c.u = u;
  return c.f;
}
__device__ __forceinline__ float dpp_shr4(float own, float src) {
  union { float f; int i; } o, s, r;
  o.f = own; s.f = src;
  r.i = __builtin_amdgcn_update_dpp(o.i, s.i, 0x114, 0xF, 0xA, false);
  return r.f;
}
__device__ __forceinline__ float dpp_shr8(float own, float src) {
  union { float f; int i; } o, s, r;
  o.f = own; s.f = src;
  r.i = __builtin_amdgcn_update_dpp(o.i, s.i, 0x118, 0xF, 0xC, false);
  return r.f;
}
__device__ __forceinline__ float dpp_shr2(float x) {
  union { float f; int i; } s, r;
  s.f = x;
  r.i = __builtin_amdgcn_update_dpp(s.i, s.i, 0x112, 0xF, 0xF, false);
  return r.f;
}
// quad_perm [2,3,0,1]: lane q gets value from lane q^2 (pair partner)
__device__ __forceinline__ float dpp_swap2(float x) {
  union { float f; int i; } s, r;
  s.f = x;
  r.i = __builtin_amdgcn_update_dpp(s.i, s.i, 0x4E, 0xF, 0xF, false);
  return r.f;
}

// resets dtype ambiguous (reference dtype bool). flags[0]=float32, flags[1]=bytes.
__global__ void detect_resets(const int* __restrict__ r, int n, int* __restrict__ flags) {
  int isf = 0, oth = 0;
  for (int i = blockIdx.x * blockDim.x + threadIdx.x; i < n; i += gridDim.x * blockDim.x) {
    int v = r[i];
    if (v == 0x3F800000) isf = 1;
    else if (v != 0 && v != 1) oth = 1;
  }
  if (isf) atomicOr(&flags[0], 1);
  if (oth) atomicOr(&flags[1], 1);
}

__device__ __forceinline__ int read_reset(const void* r, int f0, int f1, int idx) {
  if (f0) return ((const float*)r)[idx] != 0.0f;
  if (f1) return ((const unsigned char*)r)[idx] != 0;
  return ((const int*)r)[idx] != 0;
}

__global__ void convert_resets(const void* __restrict__ rst, const int* __restrict__ flags,
                               unsigned char* __restrict__ rst8) {
  int f0 = flags[0], f1 = flags[1];
  for (int i = blockIdx.x * blockDim.x + threadIdx.x; i < T_DIM * B_DIM;
       i += gridDim.x * blockDim.x)
    rst8[i] = (unsigned char)read_reset(rst, f0, f1, i);
}

// Pack WiT (768x256 bf16, transposed Wi, PRE-SCALED per output col) and Wpk A-frags
// (PRE-SCALED): frag(dt,ks) elem (l,j) = scl(dt)*W[ks*32+(l>>4)*8+j][dt*16+(l&15)].
__global__ void pack_weights(const float* __restrict__ Wi,
                             const float* __restrict__ Whr,
                             const float* __restrict__ Whz,
                             const float* __restrict__ Whn,
                             unsigned short* __restrict__ WiT,
                             unsigned short* __restrict__ Wpk) {
  int gid = blockIdx.x * 256 + threadIdx.x;
  const int NE = 768 * 256;
  if (gid < NE) {
    int n = gid >> 8, k = gid & 255;
    float scl = (n < 512) ? SCL_RZ : SCL_N;
    WiT[gid] = f2bf(Wi[k * 768 + n] * scl);
  } else if (gid < 2 * NE) {
    int g = gid - NE;
    int j = g & 7, l = (g >> 3) & 63, ks = (g >> 9) & 7, nt = g >> 12;
    int k = ks * 32 + (l >> 4) * 8 + j;
    int col = nt * 16 + (l & 15);
    float w;
    if (col < 256)      w = Whr[k * 256 + col] * SCL_RZ;
    else if (col < 512) w = Whz[k * 256 + col - 256] * SCL_RZ;
    else                w = Whn[k * 256 + col - 512] * SCL_N;
    Wpk[g] = f2bf(w);
  }
}

// Fused kernel. even blockIdx -> scan WG (2 batch rows); odd -> producer WG.
// Producers compute xp in rounds of 128 m-blocks (64 t-steps), publish rc[r].
__global__ __launch_bounds__(512, 2) void fused(
    const float* __restrict__ x, const unsigned short* __restrict__ WiT,
    const float* __restrict__ bi, unsigned short* __restrict__ xp,
    const unsigned char* __restrict__ rst8, const float* __restrict__ bhn,
    const unsigned short* __restrict__ Wpk, float* __restrict__ y,
    float* __restrict__ hws, int* __restrict__ rc, int t0, int Tc) {
  __shared__ __align__(16) char smem[32768];
  const int tid = threadIdx.x;

  if (blockIdx.x & 1) {
    // ================= producer: xp = x@Wi_scaled + bi_scaled =================
    unsigned short* Al = (unsigned short*)smem;            // 128x64 bf16, swizzled
    unsigned short* Bl = (unsigned short*)(smem + 16384);  // 128x64 bf16, swizzled
    const int pw = blockIdx.x >> 1;
    const int l = tid & 63, wid = tid >> 6;
    const int wm = wid >> 2, wn = wid & 3;   // 2x4 wave grid over 128x128 tile
    const int Mc = Tc * 2;
    const int rounds = (Mc + 127) >> 7;
    for (int r = 0; r < rounds; ++r) {
      const int mb = r * 128 + pw;
      if (mb < Mc) {
        const long m0 = (long)mb * 128;
        for (int nb = 0; nb < 6; ++nb) {
          const int n0 = nb * 128;
          f32x4 acc[4][2] = {};
          for (int kb = 0; kb < 4; ++kb) {
            const int k0 = kb * 64;
            __syncthreads();
#pragma unroll
            for (int i = 0; i < 4; ++i) {  // stage A (x fp32 -> bf16)
              int fidx = i * 512 + tid;
              int row = fidx >> 4, kf = fidx & 15;
              float4 v = *(const float4*)&x[(m0 + row) * 256 + k0 + kf * 4];
              uint2 pk;
              pk.x = f2bf(v.x) | ((unsigned)f2bf(v.y) << 16);
              pk.y = f2bf(v.z) | ((unsigned)f2bf(v.w) << 16);
              int byte = (row * 128 + kf * 8) ^ ((row & 7) << 4);
              *(uint2*)((char*)Al + byte) = pk;
            }
#pragma unroll
            for (int i = 0; i < 2; ++i) {  // stage B (WiT bf16)
              int cidx = i * 512 + tid;
              int row = cidx >> 3, kc = cidx & 7;
              short8 v = *(const short8*)&WiT[(n0 + row) * 256 + k0 + kc * 8];
              int byte = (row * 128 + kc * 16) ^ ((row & 7) << 4);
              *(short8*)((char*)Bl + byte) = v;
            }
            __syncthreads();
#pragma unroll
            for (int kk = 0; kk < 2; ++kk) {
              short8 af[4], bfv[2];
#pragma unroll
              for (int t = 0; t < 4; ++t) {
                int m = wm * 64 + t * 16 + (l & 15);
                af[t] = *(const short8*)((char*)Al + ((m * 128 + kk * 64 + (l >> 4) * 16) ^ ((m & 7) << 4)));
              }
#pragma unroll
              for (int u = 0; u < 2; ++u) {
                int n = wn * 32 + u * 16 + (l & 15);
                bfv[u] = *(const short8*)((char*)Bl + ((n * 128 + kk * 64 + (l >> 4) * 16) ^ ((n & 7) << 4)));
              }
#pragma unroll
              for (int tm = 0; tm < 4; ++tm)
#pragma unroll
                for (int tn = 0; tn < 2; ++tn)
                  acc[tm][tn] = __builtin_amdgcn_mfma_f32_16x16x32_bf16(af[tm], bfv[tn], acc[tm][tn], 0, 0, 0);
            }
          }
#pragma unroll
          for (int tn = 0; tn < 2; ++tn) {
            int n = n0 + wn * 32 + tn * 16 + (l & 15);
            float bscl = bi[n] * ((n < 512) ? SCL_RZ : SCL_N);
#pragma unroll
            for (int tm = 0; tm < 4; ++tm) {
#pragma unroll
              for (int rr = 0; rr < 4; ++rr) {
                long m = m0 + wm * 64 + tm * 16 + (l >> 4) * 4 + rr;
                xp[m * 768 + n] = f2bf(acc[tm][tn][rr] + bscl);
              }
            }
          }
        }
      }
      __syncthreads();  // all waves' stores issued before the flag
      if (tid == 0)
        __hip_atomic_fetch_add(&rc[r], 1, __ATOMIC_RELEASE, __HIP_MEMORY_SCOPE_AGENT);
    }
    return;
  }

  // ================= consumer: recurrent scan =================
  char* hb16 = smem;  // [2][HBUF] bytes, pitch HP per batch row
  const int l = tid & 63, w = tid >> 6;
  const int p = l & 15, grp = l >> 4;
  const int b = p & 1;
  const int B0 = (blockIdx.x >> 1) * 2;
  const bool odd1 = (p >> 1) & 1;
  const int d0 = w * 32 + ((p >> 2) & 1) * 16 + grp * 4 + ((p >> 3) & 1) * 2 + ((p >> 1) & 1);

  // all 48 weight frags into registers/AGPRs
  short8 wreg[48];
#pragma unroll
  for (int t = 0; t < 6; ++t) {
    int dt = (t >> 1) * 16 + w * 2 + (t & 1);
#pragma unroll
    for (int kk = 0; kk < 8; ++kk)
      wreg[t * 8 + kk] = *(const short8*)&Wpk[((dt * 8 + kk) * 64 + l) * 8];
  }
  const float bh = bhn[d0] * SCL_N;

  // init h (1 elem) + hb16 buffer 0
  float h = 0.f;
  if (t0 > 0) {
    float hv = hws[(B0 + b) * 256 + d0];
    if (!rst8[t0 * 256 + B0 + b]) h = hv;
  }
  {
    unsigned hp;
    asm("v_cvt_pk_bf16_f32 %0, %1, %2" : "=v"(hp) : "v"(h), "v"(h));
    *(unsigned short*)(hb16 + b * HP + d0 * 2) = (unsigned short)hp;
  }
  __syncthreads();

  // wait for xp round 0, then prefetch step 0
  int done_rounds = 0;
#define WAIT_ROUNDS(rneed)                                                              \
  while (done_rounds <= (rneed)) {                                                     \
    int c_ = __hip_atomic_load(&rc[done_rounds], __ATOMIC_ACQUIRE,                     \
                               __HIP_MEMORY_SCOPE_AGENT);                              \
    if (c_ == 128) ++done_rounds;                                                      \
    else __builtin_amdgcn_s_sleep(8);                                                  \
  }
  WAIT_ROUNDS(0)

  const unsigned short* xpp = xp + ((long)(B0 + b)) * 768 + d0;
  float* yp = y + ((long)t0 * 256 + B0 + b) * 256 + d0;
  unsigned xr_ = *(const unsigned short*)(xpp);
  unsigned xz_ = *(const unsigned short*)(xpp + 256);
  unsigned xn_ = *(const unsigned short*)(xpp + 512);
  xpp += 256 * 768;
  int rstn = (t0 + 1 < T_DIM) ? (int)rst8[(t0 + 1) * 256 + B0 + b] : 0;
  const char* hrd = hb16 + b * HP + grp * 16;   // frag read base
  char* hwr = hb16 + b * HP + d0 * 2;           // merged write base (even-d0 lanes)

  for (int ts = 0; ts < Tc; ++ts) {
    const int cur = ts & 1, nxt = cur ^ 1;
    const char* hb = hrd + cur * HBUF;
    const float xrf = u2f(xr_ << 16);
    const float xzf = u2f(xz_ << 16);
    const float xnf = u2f(xn_ << 16);
#define LDH(k) (*(const short8*)(hb + (k) * 64))
    // ---- pair Z (acc for z-gate tiles) ----
    f32x4 az0 = {}, az1 = {};
    {
      short8 hf[3];
      hf[0] = LDH(0); hf[1] = LDH(1);
#pragma unroll
      for (int kk = 0; kk < 8; ++kk) {
        if (kk + 2 < 8) hf[(kk + 2) % 3] = LDH(kk + 2);
        const int s_ = kk % 3;
        az0 = __builtin_amdgcn_mfma_f32_16x16x32_bf16(wreg[16 + kk], hf[s_], az0, 0, 0, 0);
        az1 = __builtin_amdgcn_mfma_f32_16x16x32_bf16(wreg[24 + kk], hf[s_], az1, 0, 0, 0);
      }
    }
    // ---- pair R ----
    f32x4 ar0 = {}, ar1 = {};
    {
      short8 hf[3];
      hf[0] = LDH(0); hf[1] = LDH(1);
#pragma unroll
      for (int kk = 0; kk < 8; ++kk) {
        if (kk + 2 < 8) hf[(kk + 2) % 3] = LDH(kk + 2);
        const int s_ = kk % 3;
        ar0 = __builtin_amdgcn_mfma_f32_16x16x32_bf16(wreg[kk],     hf[s_], ar0, 0, 0, 0);
        ar1 = __builtin_amdgcn_mfma_f32_16x16x32_bf16(wreg[8 + kk], hf[s_], ar1, 0, 0, 0);
      }
    }
    // ---- fold Z + den_z (hides under pair R/N MFMAs) ----
    float den_z;
    {
      float f0 = dpp_shr4(az0[0], az1[0]), f1 = dpp_shr4(az0[1], az1[1]);
      float f2 = dpp_shr4(az0[2], az1[2]), f3 = dpp_shr4(az0[3], az1[3]);
      float g0 = dpp_shr8(f0, f2), g1 = dpp_shr8(f1, f3);
      float aZ = odd1 ? dpp_shr2(g1) : g0;
      den_z = 1.0f + exp2f(fminf(xzf + aZ, 14.f));
    }
    // ---- pair N ----
    f32x4 an0 = {}, an1 = {};
    {
      short8 hf[3];
      hf[0] = LDH(0); hf[1] = LDH(1);
#pragma unroll
      for (int kk = 0; kk < 8; ++kk) {
        if (kk + 2 < 8) hf[(kk + 2) % 3] = LDH(kk + 2);
        const int s_ = kk % 3;
        an0 = __builtin_amdgcn_mfma_f32_16x16x32_bf16(wreg[32 + kk], hf[s_], an0, 0, 0, 0);
        an1 = __builtin_amdgcn_mfma_f32_16x16x32_bf16(wreg[40 + kk], hf[s_], an1, 0, 0, 0);
      }
    }
#undef LDH
    // ---- fold R + den_r + shared rcp (hides under pair N MFMAs) ----
    float rg, zg;
    {
      float f0 = dpp_shr4(ar0[0], ar1[0]), f1 = dpp_shr4(ar0[1], ar1[1]);
      float f2 = dpp_shr4(ar0[2], ar1[2]), f3 = dpp_shr4(ar0[3], ar1[3]);
      float g0 = dpp_shr8(f0, f2), g1 = dpp_shr8(f1, f3);
      float aR = odd1 ? dpp_shr2(g1) : g0;
      float den_r = 1.0f + exp2f(fminf(xrf + aR, 14.f));
      float s = __builtin_amdgcn_rcpf(den_r * den_z);
      rg = den_z * s;   // 1/den_r
      zg = den_r * s;   // 1/den_z
    }
    // ---- fold N + n-gate tail (exposed) ----
    float o;
    {
      float f0 = dpp_shr4(an0[0], an1[0]), f1 = dpp_shr4(an0[1], an1[1]);
      float f2 = dpp_shr4(an0[2], an1[2]), f3 = dpp_shr4(an0[3], an1[3]);
      float g0 = dpp_shr8(f0, f2), g1 = dpp_shr8(f1, f3);
      float aN = odd1 ? dpp_shr2(g1) : g0;
      float cden = 1.0f + exp2f(fminf(fmaf(rg, aN + bh, xnf), 14.f));
      float ic = __builtin_amdgcn_rcpf(cden);
      float ng = fmaf(-2.0f, ic, 1.0f);          // tanh
      o = fmaf(zg, h - ng, ng);                  // o = n + z*(h-n)
    }
    *yp = o;
    yp += 256 * 256;
    // carry (mask with next step's reset); pair-merged dword write
    h = rstn ? 0.f : o;
    {
      float hq = dpp_swap2(h);   // partner lane (p^2) holds d0^1
      if ((p & 2) == 0) {        // even-d0 lanes write (h[d0], h[d0+1]) as one dword
        unsigned hp;
        asm("v_cvt_pk_bf16_f32 %0, %1, %2" : "=v"(hp) : "v"(h), "v"(hq));
        *(unsigned*)(hwr + nxt * HBUF) = hp;
      }
    }
    // prefetch next step (vmcnt NOT drained at barrier)
    if (ts + 1 < Tc) {
      WAIT_ROUNDS((2 * ts + 3) >> 7)
      xr_ = *(const unsigned short*)(xpp);
      xz_ = *(const unsigned short*)(xpp + 256);
      xn_ = *(const unsigned short*)(xpp + 512);
      xpp += 256 * 768;
      int tg = t0 + ts;
      rstn = (tg + 2 < T_DIM) ? (int)rst8[(tg + 2) * 256 + B0 + b] : 0;
    }
    asm volatile("s_waitcnt lgkmcnt(0)" ::: "memory");
    __builtin_amdgcn_s_barrier();
  }
#undef WAIT_ROUNDS
  hws[(B0 + b) * 256 + d0] = h;
}

extern "C" void kernel_launch(void* const* d_in, const int* in_sizes, int n_in,
                              void* d_out, int out_size, void* d_ws, size_t ws_size,
                              hipStream_t stream) {
  const float* x    = (const float*)d_in[0];
  const void*  rst  = d_in[1];
  const float* Wi   = (const float*)d_in[2];
  const float* bi   = (const float*)d_in[3];
  const float* Whr  = (const float*)d_in[4];
  const float* Whz  = (const float*)d_in[5];
  const float* Whn  = (const float*)d_in[6];
  const float* bhn  = (const float*)d_in[7];
  float* y = (float*)d_out;

  char* ws = (char*)d_ws;
  unsigned short* Wpk = (unsigned short*)(ws);              // 393216 B
  unsigned short* WiT = (unsigned short*)(ws + 393216);     // 393216 B
  float* hws          = (float*)(ws + 786432);              // 262144 B
  int* flags          = (int*)(ws + 1048576);               // 64 B
  int* rc             = (int*)(ws + 1048640);               // 64 B (16 rounds)
  unsigned char* rst8 = (unsigned char*)(ws + 1048832);     // 262144 B
  unsigned short* xpb = (unsigned short*)(ws + 1310976);

  const size_t fixed = 1310976;
  int Tc = T_DIM;
  while (Tc > 1 && fixed + (size_t)Tc * B_DIM * 768 * 2 > ws_size) Tc >>= 1;

  hipMemsetAsync(flags, 0, 8, stream);
  detect_resets<<<64, 256, 0, stream>>>((const int*)rst, T_DIM * B_DIM / 4, flags);
  convert_resets<<<256, 256, 0, stream>>>(rst, flags, rst8);
  pack_weights<<<1536, 256, 0, stream>>>(Wi, Whr, Whz, Whn, WiT, Wpk);
  for (int t0 = 0; t0 < T_DIM; t0 += Tc) {
    hipMemsetAsync(rc, 0, 64, stream);
    fused<<<256, 512, 0, stream>>>(x + (long)t0 * B_DIM * D_DIM, WiT, bi, xpb,
                                   rst8, bhn, Wpk, y, hws, rc, t0, Tc);
  }
}

// Round 9
// 1454.219 us; speedup vs baseline: 1.0379x; 1.0379x over previous
//
#include <hip/hip_runtime.h>

// GRU scan: T=1024, B=256, D=256.
// v9: v7 fused producer/consumer + HP=576 bank fix (v8, kept: conflicts->0) +
// 3+3 MFMA half-split: half A = {az0,az1,ar0}, half B = {ar1,an0,an1}, each
// kk-loop interleaves 3 independent accumulators (pipe stays saturated, unlike
// v8's 2-acc pairs). Z fold+exp2 and R fold+rcp hide under half B's drain;
// only the N tail is exposed.

typedef __attribute__((ext_vector_type(8))) short short8;
typedef __attribute__((ext_vector_type(4))) float f32x4;

#define T_DIM 1024
#define B_DIM 256
#define D_DIM 256
#define SCL_RZ (-1.44269504f)   // -log2(e): sigm(x) = 1/(1+exp2(x*SCL_RZ))
#define SCL_N  (2.88539008f)    // 2*log2(e): tanh(v) = 1-2/(1+exp2(v*SCL_N))
#define HP 576                  // hb16 row pitch (bytes): +64B bank skew
#define HBUF 1152               // one h double-buffer half (2 rows x 576)

__device__ __forceinline__ unsigned short f2bf(float f) {
  union { float f; unsigned u; } c; c.f = f;
  unsigned r = c.u + 0x7FFFu + ((c.u >> 16) & 1u);  // RNE
  return (unsigned short)(r >> 16);
}
__device__ __forceinline__ float u2f(unsigned u) {
  union { unsigned u; float f; } c; c.u = u;
  return c.f;
}
__device__ __forceinline__ float dpp_shr4(float own, float src) {
  union { float f; int i; } o, s, r;
  o.f = own; s.f = src;
  r.i = __builtin_amdgcn_update_dpp(o.i, s.i, 0x114, 0xF, 0xA, false);
  return r.f;
}
__device__ __forceinline__ float dpp_shr8(float own, float src) {
  union { float f; int i; } o, s, r;
  o.f = own; s.f = src;
  r.i = __builtin_amdgcn_update_dpp(o.i, s.i, 0x118, 0xF, 0xC, false);
  return r.f;
}
__device__ __forceinline__ float dpp_shr2(float x) {
  union { float f; int i; } s, r;
  s.f = x;
  r.i = __builtin_amdgcn_update_dpp(s.i, s.i, 0x112, 0xF, 0xF, false);
  return r.f;
}
// quad_perm [2,3,0,1]: lane q gets value from lane q^2 (pair partner)
__device__ __forceinline__ float dpp_swap2(float x) {
  union { float f; int i; } s, r;
  s.f = x;
  r.i = __builtin_amdgcn_update_dpp(s.i, s.i, 0x4E, 0xF, 0xF, false);
  return r.f;
}

// resets dtype ambiguous (reference dtype bool). flags[0]=float32, flags[1]=bytes.
__global__ void detect_resets(const int* __restrict__ r, int n, int* __restrict__ flags) {
  int isf = 0, oth = 0;
  for (int i = blockIdx.x * blockDim.x + threadIdx.x; i < n; i += gridDim.x * blockDim.x) {
    int v = r[i];
    if (v == 0x3F800000) isf = 1;
    else if (v != 0 && v != 1) oth = 1;
  }
  if (isf) atomicOr(&flags[0], 1);
  if (oth) atomicOr(&flags[1], 1);
}

__device__ __forceinline__ int read_reset(const void* r, int f0, int f1, int idx) {
  if (f0) return ((const float*)r)[idx] != 0.0f;
  if (f1) return ((const unsigned char*)r)[idx] != 0;
  return ((const int*)r)[idx] != 0;
}

__global__ void convert_resets(const void* __restrict__ rst, const int* __restrict__ flags,
                               unsigned char* __restrict__ rst8) {
  int f0 = flags[0], f1 = flags[1];
  for (int i = blockIdx.x * blockDim.x + threadIdx.x; i < T_DIM * B_DIM;
       i += gridDim.x * blockDim.x)
    rst8[i] = (unsigned char)read_reset(rst, f0, f1, i);
}

// Pack WiT (768x256 bf16, transposed Wi, PRE-SCALED per output col) and Wpk A-frags
// (PRE-SCALED): frag(dt,ks) elem (l,j) = scl(dt)*W[ks*32+(l>>4)*8+j][dt*16+(l&15)].
__global__ void pack_weights(const float* __restrict__ Wi,
                             const float* __restrict__ Whr,
                             const float* __restrict__ Whz,
                             const float* __restrict__ Whn,
                             unsigned short* __restrict__ WiT,
                             unsigned short* __restrict__ Wpk) {
  int gid = blockIdx.x * 256 + threadIdx.x;
  const int NE = 768 * 256;
  if (gid < NE) {
    int n = gid >> 8, k = gid & 255;
    float scl = (n < 512) ? SCL_RZ : SCL_N;
    WiT[gid] = f2bf(Wi[k * 768 + n] * scl);
  } else if (gid < 2 * NE) {
    int g = gid - NE;
    int j = g & 7, l = (g >> 3) & 63, ks = (g >> 9) & 7, nt = g >> 12;
    int k = ks * 32 + (l >> 4) * 8 + j;
    int col = nt * 16 + (l & 15);
    float w;
    if (col < 256)      w = Whr[k * 256 + col] * SCL_RZ;
    else if (col < 512) w = Whz[k * 256 + col - 256] * SCL_RZ;
    else                w = Whn[k * 256 + col - 512] * SCL_N;
    Wpk[g] = f2bf(w);
  }
}

// Fused kernel. even blockIdx -> scan WG (2 batch rows); odd -> producer WG.
// Producers compute xp in rounds of 128 m-blocks (64 t-steps), publish rc[r].
__global__ __launch_bounds__(512, 2) void fused(
    const float* __restrict__ x, const unsigned short* __restrict__ WiT,
    const float* __restrict__ bi, unsigned short* __restrict__ xp,
    const unsigned char* __restrict__ rst8, const float* __restrict__ bhn,
    const unsigned short* __restrict__ Wpk, float* __restrict__ y,
    float* __restrict__ hws, int* __restrict__ rc, int t0, int Tc) {
  __shared__ __align__(16) char smem[32768];
  const int tid = threadIdx.x;

  if (blockIdx.x & 1) {
    // ================= producer: xp = x@Wi_scaled + bi_scaled =================
    unsigned short* Al = (unsigned short*)smem;            // 128x64 bf16, swizzled
    unsigned short* Bl = (unsigned short*)(smem + 16384);  // 128x64 bf16, swizzled
    const int pw = blockIdx.x >> 1;
    const int l = tid & 63, wid = tid >> 6;
    const int wm = wid >> 2, wn = wid & 3;   // 2x4 wave grid over 128x128 tile
    const int Mc = Tc * 2;
    const int rounds = (Mc + 127) >> 7;
    for (int r = 0; r < rounds; ++r) {
      const int mb = r * 128 + pw;
      if (mb < Mc) {
        const long m0 = (long)mb * 128;
        for (int nb = 0; nb < 6; ++nb) {
          const int n0 = nb * 128;
          f32x4 acc[4][2] = {};
          for (int kb = 0; kb < 4; ++kb) {
            const int k0 = kb * 64;
            __syncthreads();
#pragma unroll
            for (int i = 0; i < 4; ++i) {  // stage A (x fp32 -> bf16)
              int fidx = i * 512 + tid;
              int row = fidx >> 4, kf = fidx & 15;
              float4 v = *(const float4*)&x[(m0 + row) * 256 + k0 + kf * 4];
              uint2 pk;
              pk.x = f2bf(v.x) | ((unsigned)f2bf(v.y) << 16);
              pk.y = f2bf(v.z) | ((unsigned)f2bf(v.w) << 16);
              int byte = (row * 128 + kf * 8) ^ ((row & 7) << 4);
              *(uint2*)((char*)Al + byte) = pk;
            }
#pragma unroll
            for (int i = 0; i < 2; ++i) {  // stage B (WiT bf16)
              int cidx = i * 512 + tid;
              int row = cidx >> 3, kc = cidx & 7;
              short8 v = *(const short8*)&WiT[(n0 + row) * 256 + k0 + kc * 8];
              int byte = (row * 128 + kc * 16) ^ ((row & 7) << 4);
              *(short8*)((char*)Bl + byte) = v;
            }
            __syncthreads();
#pragma unroll
            for (int kk = 0; kk < 2; ++kk) {
              short8 af[4], bfv[2];
#pragma unroll
              for (int t = 0; t < 4; ++t) {
                int m = wm * 64 + t * 16 + (l & 15);
                af[t] = *(const short8*)((char*)Al + ((m * 128 + kk * 64 + (l >> 4) * 16) ^ ((m & 7) << 4)));
              }
#pragma unroll
              for (int u = 0; u < 2; ++u) {
                int n = wn * 32 + u * 16 + (l & 15);
                bfv[u] = *(const short8*)((char*)Bl + ((n * 128 + kk * 64 + (l >> 4) * 16) ^ ((n & 7) << 4)));
              }
#pragma unroll
              for (int tm = 0; tm < 4; ++tm)
#pragma unroll
                for (int tn = 0; tn < 2; ++tn)
                  acc[tm][tn] = __builtin_amdgcn_mfma_f32_16x16x32_bf16(af[tm], bfv[tn], acc[tm][tn], 0, 0, 0);
            }
          }
#pragma unroll
          for (int tn = 0; tn < 2; ++tn) {
            int n = n0 + wn * 32 + tn * 16 + (l & 15);
            float bscl = bi[n] * ((n < 512) ? SCL_RZ : SCL_N);
#pragma unroll
            for (int tm = 0; tm < 4; ++tm) {
#pragma unroll
              for (int rr = 0; rr < 4; ++rr) {
                long m = m0 + wm * 64 + tm * 16 + (l >> 4) * 4 + rr;
                xp[m * 768 + n] = f2bf(acc[tm][tn][rr] + bscl);
              }
            }
          }
        }
      }
      __syncthreads();  // all waves' stores issued before the flag
      if (tid == 0)
        __hip_atomic_fetch_add(&rc[r], 1, __ATOMIC_RELEASE, __HIP_MEMORY_SCOPE_AGENT);
    }
    return;
  }

  // ================= consumer: recurrent scan =================
  char* hb16 = smem;  // [2][HBUF] bytes, pitch HP per batch row
  const int l = tid & 63, w = tid >> 6;
  const int p = l & 15, grp = l >> 4;
  const int b = p & 1;
  const int B0 = (blockIdx.x >> 1) * 2;
  const bool odd1 = (p >> 1) & 1;
  const int d0 = w * 32 + ((p >> 2) & 1) * 16 + grp * 4 + ((p >> 3) & 1) * 2 + ((p >> 1) & 1);

  // all 48 weight frags into registers/AGPRs
  short8 wreg[48];
#pragma unroll
  for (int t = 0; t < 6; ++t) {
    int dt = (t >> 1) * 16 + w * 2 + (t & 1);
#pragma unroll
    for (int kk = 0; kk < 8; ++kk)
      wreg[t * 8 + kk] = *(const short8*)&Wpk[((dt * 8 + kk) * 64 + l) * 8];
  }
  const float bh = bhn[d0] * SCL_N;

  // init h (1 elem) + hb16 buffer 0
  float h = 0.f;
  if (t0 > 0) {
    float hv = hws[(B0 + b) * 256 + d0];
    if (!rst8[t0 * 256 + B0 + b]) h = hv;
  }
  {
    unsigned hp;
    asm("v_cvt_pk_bf16_f32 %0, %1, %2" : "=v"(hp) : "v"(h), "v"(h));
    *(unsigned short*)(hb16 + b * HP + d0 * 2) = (unsigned short)hp;
  }
  __syncthreads();

  // wait for xp round 0, then prefetch step 0
  int done_rounds = 0;
#define WAIT_ROUNDS(rneed)                                                              \
  while (done_rounds <= (rneed)) {                                                     \
    int c_ = __hip_atomic_load(&rc[done_rounds], __ATOMIC_ACQUIRE,                     \
                               __HIP_MEMORY_SCOPE_AGENT);                              \
    if (c_ == 128) ++done_rounds;                                                      \
    else __builtin_amdgcn_s_sleep(8);                                                  \
  }
  WAIT_ROUNDS(0)

  const unsigned short* xpp = xp + ((long)(B0 + b)) * 768 + d0;
  float* yp = y + ((long)t0 * 256 + B0 + b) * 256 + d0;
  unsigned xr_ = *(const unsigned short*)(xpp);
  unsigned xz_ = *(const unsigned short*)(xpp + 256);
  unsigned xn_ = *(const unsigned short*)(xpp + 512);
  xpp += 256 * 768;
  int rstn = (t0 + 1 < T_DIM) ? (int)rst8[(t0 + 1) * 256 + B0 + b] : 0;
  const char* hrd = hb16 + b * HP + grp * 16;   // frag read base
  char* hwr = hb16 + b * HP + d0 * 2;           // merged write base (even-d0 lanes)

  for (int ts = 0; ts < Tc; ++ts) {
    const int cur = ts & 1, nxt = cur ^ 1;
    const char* hb = hrd + cur * HBUF;
    const float xrf = u2f(xr_ << 16);
    const float xzf = u2f(xz_ << 16);
    const float xnf = u2f(xn_ << 16);
#define LDH(k) (*(const short8*)(hb + (k) * 64))
    // ---- half A: {az0, az1, ar0} interleaved (3-deep MFMA ILP) ----
    f32x4 az0 = {}, az1 = {}, ar0 = {};
    {
      short8 hf[3];
      hf[0] = LDH(0); hf[1] = LDH(1);
#pragma unroll
      for (int kk = 0; kk < 8; ++kk) {
        if (kk + 2 < 8) hf[(kk + 2) % 3] = LDH(kk + 2);
        const int s_ = kk % 3;
        az0 = __builtin_amdgcn_mfma_f32_16x16x32_bf16(wreg[16 + kk], hf[s_], az0, 0, 0, 0);
        az1 = __builtin_amdgcn_mfma_f32_16x16x32_bf16(wreg[24 + kk], hf[s_], az1, 0, 0, 0);
        ar0 = __builtin_amdgcn_mfma_f32_16x16x32_bf16(wreg[kk],      hf[s_], ar0, 0, 0, 0);
      }
    }
    // ---- half B: {ar1, an0, an1} interleaved (ar1 first -> retires earliest) ----
    f32x4 ar1 = {}, an0 = {}, an1 = {};
    {
      short8 hf[3];
      hf[0] = LDH(0); hf[1] = LDH(1);
#pragma unroll
      for (int kk = 0; kk < 8; ++kk) {
        if (kk + 2 < 8) hf[(kk + 2) % 3] = LDH(kk + 2);
        const int s_ = kk % 3;
        ar1 = __builtin_amdgcn_mfma_f32_16x16x32_bf16(wreg[8 + kk],  hf[s_], ar1, 0, 0, 0);
        an0 = __builtin_amdgcn_mfma_f32_16x16x32_bf16(wreg[32 + kk], hf[s_], an0, 0, 0, 0);
        an1 = __builtin_amdgcn_mfma_f32_16x16x32_bf16(wreg[40 + kk], hf[s_], an1, 0, 0, 0);
      }
    }
#undef LDH
    // ---- fold Z + den_z (az retired during half B's issue/drain) ----
    float den_z;
    {
      float f0 = dpp_shr4(az0[0], az1[0]), f1 = dpp_shr4(az0[1], az1[1]);
      float f2 = dpp_shr4(az0[2], az1[2]), f3 = dpp_shr4(az0[3], az1[3]);
      float g0 = dpp_shr8(f0, f2), g1 = dpp_shr8(f1, f3);
      float aZ = odd1 ? dpp_shr2(g1) : g0;
      den_z = 1.0f + exp2f(fminf(xzf + aZ, 14.f));
    }
    // ---- fold R + den_r + shared rcp (ar1 retires early in half B drain) ----
    float rg, zg;
    {
      float f0 = dpp_shr4(ar0[0], ar1[0]), f1 = dpp_shr4(ar0[1], ar1[1]);
      float f2 = dpp_shr4(ar0[2], ar1[2]), f3 = dpp_shr4(ar0[3], ar1[3]);
      float g0 = dpp_shr8(f0, f2), g1 = dpp_shr8(f1, f3);
      float aR = odd1 ? dpp_shr2(g1) : g0;
      float den_r = 1.0f + exp2f(fminf(xrf + aR, 14.f));
      float s = __builtin_amdgcn_rcpf(den_r * den_z);
      rg = den_z * s;   // 1/den_r
      zg = den_r * s;   // 1/den_z
    }
    // ---- fold N + n-gate tail (exposed) ----
    float o;
    {
      float f0 = dpp_shr4(an0[0], an1[0]), f1 = dpp_shr4(an0[1], an1[1]);
      float f2 = dpp_shr4(an0[2], an1[2]), f3 = dpp_shr4(an0[3], an1[3]);
      float g0 = dpp_shr8(f0, f2), g1 = dpp_shr8(f1, f3);
      float aN = odd1 ? dpp_shr2(g1) : g0;
      float cden = 1.0f + exp2f(fminf(fmaf(rg, aN + bh, xnf), 14.f));
      float ic = __builtin_amdgcn_rcpf(cden);
      float ng = fmaf(-2.0f, ic, 1.0f);          // tanh
      o = fmaf(zg, h - ng, ng);                  // o = n + z*(h-n)
    }
    *yp = o;
    yp += 256 * 256;
    // carry (mask with next step's reset); pair-merged dword write
    h = rstn ? 0.f : o;
    {
      float hq = dpp_swap2(h);   // partner lane (p^2) holds d0^1
      if ((p & 2) == 0) {        // even-d0 lanes write (h[d0], h[d0+1]) as one dword
        unsigned hp;
        asm("v_cvt_pk_bf16_f32 %0, %1, %2" : "=v"(hp) : "v"(h), "v"(hq));
        *(unsigned*)(hwr + nxt * HBUF) = hp;
      }
    }
    // prefetch next step (vmcnt NOT drained at barrier)
    if (ts + 1 < Tc) {
      WAIT_ROUNDS((2 * ts + 3) >> 7)
      xr_ = *(const unsigned short*)(xpp);
      xz_ = *(const unsigned short*)(xpp + 256);
      xn_ = *(const unsigned short*)(xpp + 512);
      xpp += 256 * 768;
      int tg = t0 + ts;
      rstn = (tg + 2 < T_DIM) ? (int)rst8[(tg + 2) * 256 + B0 + b] : 0;
    }
    asm volatile("s_waitcnt lgkmcnt(0)" ::: "memory");
    __builtin_amdgcn_s_barrier();
  }
#undef WAIT_ROUNDS
  hws[(B0 + b) * 256 + d0] = h;
}

extern "C" void kernel_launch(void* const* d_in, const int* in_sizes, int n_in,
                              void* d_out, int out_size, void* d_ws, size_t ws_size,
                              hipStream_t stream) {
  const float* x    = (const float*)d_in[0];
  const void*  rst  = d_in[1];
  const float* Wi   = (const float*)d_in[2];
  const float* bi   = (const float*)d_in[3];
  const float* Whr  = (const float*)d_in[4];
  const float* Whz  = (const float*)d_in[5];
  const float* Whn  = (const float*)d_in[6];
  const float* bhn  = (const float*)d_in[7];
  float* y = (float*)d_out;

  char* ws = (char*)d_ws;
  unsigned short* Wpk = (unsigned short*)(ws);              // 393216 B
  unsigned short* WiT = (unsigned short*)(ws + 393216);     // 393216 B
  float* hws          = (float*)(ws + 786432);              // 262144 B
  int* flags          = (int*)(ws + 1048576);               // 64 B
  int* rc             = (int*)(ws + 1048640);               // 64 B (16 rounds)
  unsigned char* rst8 = (unsigned char*)(ws + 1048832);     // 262144 B
  unsigned short* xpb = (unsigned short*)(ws + 1310976);

  const size_t fixed = 1310976;
  int Tc = T_DIM;
  while (Tc > 1 && fixed + (size_t)Tc * B_DIM * 768 * 2 > ws_size) Tc >>= 1;

  hipMemsetAsync(flags, 0, 8, stream);
  detect_resets<<<64, 256, 0, stream>>>((const int*)rst, T_DIM * B_DIM / 4, flags);
  convert_resets<<<256, 256, 0, stream>>>(rst, flags, rst8);
  pack_weights<<<1536, 256, 0, stream>>>(Wi, Whr, Whz, Whn, WiT, Wpk);
  for (int t0 = 0; t0 < T_DIM; t0 += Tc) {
    hipMemsetAsync(rc, 0, 64, stream);
    fused<<<256, 512, 0, stream>>>(x + (long)t0 * B_DIM * D_DIM, WiT, bi, xpb,
                                   rst8, bhn, Wpk, y, hws, rc, t0, Tc);
  }
}